// Round 6
// baseline (909.928 us; speedup 1.0000x reference)
//
#include <hip/hip_runtime.h>
#include <hip/hip_bf16.h>

typedef float f32x4 __attribute__((ext_vector_type(4)));
typedef short s16x8 __attribute__((ext_vector_type(8)));

__device__ __forceinline__ unsigned short f2bf(float f) {
  union { float f; unsigned int u; } v;
  v.f = f;
  unsigned int u = v.u;
  u += 0x7fffu + ((u >> 16) & 1u);   // round-to-nearest-even (finite data only)
  return (unsigned short)(u >> 16);
}

struct GemmArgs {
  const float* W[4];
  const float* Bi[4];
};

// Y[e] = act(X[e] (64xK, bf16) @ W[e]^T (NxK, f32) + bias[e])
// LDS-FREE, BARRIER-FREE: one wave per block, wave owns a 64(M)x16(N) tile.
// B-fragments (W rows) are loaded straight from global f32 -> cvt -> MFMA
// operand registers; the MFMA b-frag lane map (col=lane&15, k=(lane>>4)*8)
// is exactly a 16-row x 8-elem slice of row-major W, so no staging/transpose
// is needed. No vmcnt coupling: the compiler pipelines the 6 wave-wide loads
// per k-step freely (no barriers), ~2 k-steps in flight = 12 KB/wave.
// Grid: (N/16, 4 experts), 64-thread blocks -> 768 blocks (3 waves/CU) hidden.
template<bool GELU, bool OUTBF16>
__global__ __launch_bounds__(64) void mlp_gemm(
    const unsigned short* __restrict__ X, unsigned long long xstride,
    GemmArgs args,
    void* __restrict__ Y, unsigned long long ystride,
    int N, int K)
{
  const int e    = blockIdx.y;
  const int n0   = blockIdx.x * 16;
  const int lane = threadIdx.x & 63;

  const float* __restrict__ Wg = args.W[e];
  const unsigned short* __restrict__ Xg = X + (size_t)e * xstride;

  const int frow = lane & 15;          // N-row within b-frag / M-row within a-frag
  const int bk8  = (lane >> 4) << 3;   // k sub-offset (8 elements)

  const float*          __restrict__ wrow = Wg + (size_t)(n0 + frow) * K + bk8;
  const unsigned short* __restrict__ xrow = Xg + (size_t)frow * K + bk8;
  const size_t mstride = (size_t)16 * K;

  f32x4 acc[4];
#pragma unroll
  for (int m = 0; m < 4; ++m) acc[m] = {0.f, 0.f, 0.f, 0.f};

#pragma unroll 4
  for (int k = 0; k < K; k += 32) {
    const f32x4 wlo = *(const f32x4*)(wrow + k);
    const f32x4 whi = *(const f32x4*)(wrow + k + 4);
    s16x8 b;
    b[0] = (short)f2bf(wlo[0]); b[1] = (short)f2bf(wlo[1]);
    b[2] = (short)f2bf(wlo[2]); b[3] = (short)f2bf(wlo[3]);
    b[4] = (short)f2bf(whi[0]); b[5] = (short)f2bf(whi[1]);
    b[6] = (short)f2bf(whi[2]); b[7] = (short)f2bf(whi[3]);
#pragma unroll
    for (int m = 0; m < 4; ++m) {
      const s16x8 a = *(const s16x8*)(xrow + (size_t)m * mstride + k);
      acc[m] = __builtin_amdgcn_mfma_f32_16x16x32_bf16(a, b, acc[m], 0, 0, 0);
    }
  }

  // epilogue: D frag mapping col = lane&15, row = (lane>>4)*4 + reg  [m89-verified]
  const float* __restrict__ Bi = args.Bi[e];
  const int col = lane & 15;
  const int nn  = n0 + col;
  const float bv = Bi[nn];
  const int rsub = (lane >> 4) << 2;
#pragma unroll
  for (int m = 0; m < 4; ++m) {
#pragma unroll
    for (int r = 0; r < 4; ++r) {
      float yv = acc[m][r] + bv;
      if (GELU) yv = 0.5f * yv * (1.0f + erff(yv * 0.70710678118654752f));
      const size_t oidx = (size_t)e * ystride + (size_t)(m * 16 + rsub + r) * N + nn;
      if (OUTBF16) ((unsigned short*)Y)[oidx] = f2bf(yv);
      else         ((float*)Y)[oidx] = yv;
    }
  }
}

__global__ __launch_bounds__(256) void cvt_u_kernel(
    const float* __restrict__ u, unsigned short* __restrict__ ub)
{
  const int i = blockIdx.x * 256 + threadIdx.x;
  ub[i] = f2bf(u[i]);
}

// out[b,i,j] = base[i,j] + sum_r v1[r,b,i] * v2[r,b,j]
template<int D1, int D2>
__device__ __forceinline__ void synth_body(
    const float* __restrict__ Wbase, const float* __restrict__ V,
    float* __restrict__ Out)
{
  constexpr int QPR = D2 / 4;          // quads per output row
  constexpr int RP  = 256 / QPR;       // rows processed in parallel
  constexpr size_t S = (size_t)64 * 1536;
  const int i0 = blockIdx.x * 32;
  if (i0 >= D1) return;                // fused-grid overshoot for the smaller D1
  const int b    = blockIdx.y;
  const int isub = threadIdx.x / QPR;
  const int jq   = threadIdx.x % QPR;
  const float* __restrict__ vb = V + (size_t)b * 1536;
  const f32x4 v2a = *(const f32x4*)(vb + D1 + jq * 4);
  const f32x4 v2b = *(const f32x4*)(vb + S + D1 + jq * 4);
#pragma unroll
  for (int ii = isub; ii < 32; ii += RP) {
    const int i = i0 + ii;
    const float a0 = vb[i];
    const float a1 = vb[S + i];
    const f32x4 w = *(const f32x4*)(Wbase + (size_t)i * D2 + jq * 4);
    f32x4 o = w + a0 * v2a + a1 * v2b;
    *(f32x4*)(Out + ((size_t)b * D1 + i) * D2 + jq * 4) = o;
  }
}

// Both synth stages in ONE kernel so it ranks in the rocprof top-5 if slow.
__global__ __launch_bounds__(256) void synth_fused(
    const float* __restrict__ w1, const float* __restrict__ w2,
    const float* __restrict__ V, float* __restrict__ Out)
{
  if (blockIdx.z == 0) {
    synth_body<1024, 512>(w1, V, Out);
  } else {
    synth_body<512, 1024>(w2, V + (size_t)2 * 64 * 1536,
                          Out + (size_t)64 * 1024 * 512);
  }
}

extern "C" void kernel_launch(void* const* d_in, const int* in_sizes, int n_in,
                              void* d_out, int out_size, void* d_ws, size_t ws_size,
                              hipStream_t stream) {
  const int Hh = 3072, IND = 256, OD = 1536;

  const float* u0  = (const float*)d_in[0];
  const float* w1  = (const float*)d_in[1];
  const float* w2  = (const float*)d_in[2];
  const float* win[2] = {(const float*)d_in[3], (const float*)d_in[9]};
  const float* bin[2] = {(const float*)d_in[4], (const float*)d_in[10]};
  const float* hw [2] = {(const float*)d_in[5], (const float*)d_in[11]};
  const float* hb [2] = {(const float*)d_in[6], (const float*)d_in[12]};
  const float* wou[2] = {(const float*)d_in[7], (const float*)d_in[13]};
  const float* bou[2] = {(const float*)d_in[8], (const float*)d_in[14]};

  char* ws = (char*)d_ws;
  unsigned short* ub = (unsigned short*)ws;                          // 32 KB
  unsigned short* hA = (unsigned short*)(ws + (64 << 10));           // 1.5 MB
  unsigned short* hB = (unsigned short*)(ws + (64 << 10) + (2 << 20));
  float*          vv = (float*)(ws + (64 << 10) + (4 << 20));        // 1.5 MB

  cvt_u_kernel<<<64, 256, 0, stream>>>(u0, ub);

  GemmArgs ga;
  // layer-in: K=256, N=3072
  for (int e = 0; e < 4; ++e) {
    const int n = e >> 1, r = e & 1;
    ga.W[e]  = win[n] + (size_t)r * Hh * IND;
    ga.Bi[e] = bin[n] + (size_t)r * Hh;
  }
  mlp_gemm<true, true><<<dim3(Hh / 16, 4), 64, 0, stream>>>(
      ub, 0ull, ga, hA, (unsigned long long)64 * Hh, Hh, IND);

  // hidden layers: K=N=3072
  for (int l = 0; l < 2; ++l) {
    for (int e = 0; e < 4; ++e) {
      const int n = e >> 1, r = e & 1;
      ga.W[e]  = hw[n] + (size_t)(r * 2 + l) * Hh * Hh;
      ga.Bi[e] = hb[n] + (size_t)(r * 2 + l) * Hh;
    }
    const unsigned short* xin = (l == 0) ? hA : hB;
    unsigned short*      yout = (l == 0) ? hB : hA;
    mlp_gemm<true, true><<<dim3(Hh / 16, 4), 64, 0, stream>>>(
        xin, (unsigned long long)64 * Hh, ga, yout, (unsigned long long)64 * Hh, Hh, Hh);
  }

  // out layer: K=3072, N=1536, f32 out, no activation
  for (int e = 0; e < 4; ++e) {
    const int n = e >> 1, r = e & 1;
    ga.W[e]  = wou[n] + (size_t)r * OD * Hh;
    ga.Bi[e] = bou[n] + (size_t)r * OD;
  }
  mlp_gemm<false, false><<<dim3(OD / 16, 4), 64, 0, stream>>>(
      hA, (unsigned long long)64 * Hh, ga, vv, (unsigned long long)64 * OD, OD, Hh);

  float* out = (float*)d_out;
  synth_fused<<<dim3(32, 64, 2), 256, 0, stream>>>(w1, w2, vv, out);
}